// Round 1
// baseline (1213.689 us; speedup 1.0000x reference)
//
#include <hip/hip_runtime.h>
#include <math.h>

#define NLEVELS 16
#define LOG2_T 19
#define TSIZE (1u << LOG2_T)
#define TMASK (TSIZE - 1u)
#define NPTS 1048576

struct Res16 { float r[NLEVELS]; };

// One thread per (point, level). Wave64 covers 4 points x 16 levels;
// out store is fully coalesced (64 lanes x 8B float2 = 512B contiguous).
__global__ __launch_bounds__(256) void HashGridEncoder_68925635166659_kernel(
    const float* __restrict__ x,
    const float2* __restrict__ table,
    float2* __restrict__ out,
    Res16 res)
{
    const int t = blockIdx.x * blockDim.x + threadIdx.x;
    const int n = t >> 4;        // point index
    const int l = t & 15;        // level index

    const float px = x[3 * n + 0];
    const float py = x[3 * n + 1];
    const float pz = x[3 * n + 2];
    const float r  = res.r[l];

    // Match reference f32 ops exactly: mul, floor, sub.
    const float sx = px * r, sy = py * r, sz = pz * r;
    const float fx = floorf(sx), fy = floorf(sy), fz = floorf(sz);
    const float wx = sx - fx, wy = sy - fy, wz = sz - fz;

    const uint32_t ix = (uint32_t)(int)fx;
    const uint32_t iy = (uint32_t)(int)fy;
    const uint32_t iz = (uint32_t)(int)fz;

    // h = ix*P1 ^ iy*P2 ^ iz*P3  (uint32 wrap == numpy uint32)
    const uint32_t hx0 = ix;                         // P1 = 1
    const uint32_t hx1 = ix + 1u;
    const uint32_t hy0 = iy * 2654435761u;
    const uint32_t hy1 = hy0 + 2654435761u;          // (iy+1)*P2 mod 2^32
    const uint32_t hz0 = iz * 805459861u;
    const uint32_t hz1 = hz0 + 805459861u;

    const float2* __restrict__ tl = table + (uint32_t)l * TSIZE;

    // 8 independent gathers -> deep MLP, latencies overlap.
    const float2 c000 = tl[(hx0 ^ hy0 ^ hz0) & TMASK];
    const float2 c001 = tl[(hx0 ^ hy0 ^ hz1) & TMASK];
    const float2 c010 = tl[(hx0 ^ hy1 ^ hz0) & TMASK];
    const float2 c011 = tl[(hx0 ^ hy1 ^ hz1) & TMASK];
    const float2 c100 = tl[(hx1 ^ hy0 ^ hz0) & TMASK];
    const float2 c101 = tl[(hx1 ^ hy0 ^ hz1) & TMASK];
    const float2 c110 = tl[(hx1 ^ hy1 ^ hz0) & TMASK];
    const float2 c111 = tl[(hx1 ^ hy1 ^ hz1) & TMASK];

    const float wx0 = 1.0f - wx, wy0 = 1.0f - wy, wz0 = 1.0f - wz;

    float f0 = 0.0f, f1 = 0.0f;
    float w;
    // Same corner order as reference loop (dz innermost).
    w = (wx0 * wy0) * wz0; f0 += c000.x * w; f1 += c000.y * w;
    w = (wx0 * wy0) * wz;  f0 += c001.x * w; f1 += c001.y * w;
    w = (wx0 * wy ) * wz0; f0 += c010.x * w; f1 += c010.y * w;
    w = (wx0 * wy ) * wz;  f0 += c011.x * w; f1 += c011.y * w;
    w = (wx  * wy0) * wz0; f0 += c100.x * w; f1 += c100.y * w;
    w = (wx  * wy0) * wz;  f0 += c101.x * w; f1 += c101.y * w;
    w = (wx  * wy ) * wz0; f0 += c110.x * w; f1 += c110.y * w;
    w = (wx  * wy ) * wz;  f0 += c111.x * w; f1 += c111.y * w;

    out[(uint32_t)n * NLEVELS + (uint32_t)l] = make_float2(f0, f1);
}

extern "C" void kernel_launch(void* const* d_in, const int* in_sizes, int n_in,
                              void* d_out, int out_size, void* d_ws, size_t ws_size,
                              hipStream_t stream) {
    const float*  x     = (const float*)d_in[0];
    const float2* table = (const float2*)d_in[1];
    float2*       out   = (float2*)d_out;

    // Exact numpy recipe in double: floor(16 * growth^l), growth = exp(ln(256)/15)
    Res16 res;
    const double growth = exp((log(4096.0) - log(16.0)) / 15.0);
    for (int l = 0; l < NLEVELS; ++l)
        res.r[l] = (float)floor(16.0 * pow(growth, (double)l));

    const int total  = NPTS * NLEVELS;      // 16,777,216 threads
    const int block  = 256;
    const int grid   = total / block;       // 65,536 blocks

    HashGridEncoder_68925635166659_kernel<<<grid, block, 0, stream>>>(x, table, out, res);
}

// Round 3
// 869.861 us; speedup vs baseline: 1.3953x; 1.3953x over previous
//
#include <hip/hip_runtime.h>
#include <math.h>

#define NLEVELS 16
#define LOG2_T 19
#define TSIZE (1u << LOG2_T)
#define TMASK (TSIZE - 1u)
#define NPTS 1048576

typedef float vfloat2 __attribute__((ext_vector_type(2)));

struct Res16 { float r[NLEVELS]; };

// 2D grid: blockIdx.y = level, blockIdx.x = point block (256 pts).
// HIP dispatches x-fastest -> all blocks of level 0 first, etc. => temporal
// level phasing: each XCD's 4 MiB L2 holds the one active 4 MiB level slice.
// Out stores are strided (line spans 16 levels) -> nontemporal so the 134 MB
// write stream doesn't evict the table slice from L2.
__global__ __launch_bounds__(256) void HashGridEncoder_68925635166659_kernel(
    const float* __restrict__ x,
    const vfloat2* __restrict__ table,
    vfloat2* __restrict__ out,
    Res16 res)
{
    const int l = blockIdx.y;
    const int n = blockIdx.x * blockDim.x + threadIdx.x;

    const float px = __builtin_nontemporal_load(x + 3 * n + 0);
    const float py = __builtin_nontemporal_load(x + 3 * n + 1);
    const float pz = __builtin_nontemporal_load(x + 3 * n + 2);
    const float r  = res.r[l];

    // Match reference f32 ops exactly: mul, floor, sub.
    const float sx = px * r, sy = py * r, sz = pz * r;
    const float fx = floorf(sx), fy = floorf(sy), fz = floorf(sz);
    const float wx = sx - fx, wy = sy - fy, wz = sz - fz;

    const uint32_t ix = (uint32_t)(int)fx;
    const uint32_t iy = (uint32_t)(int)fy;
    const uint32_t iz = (uint32_t)(int)fz;

    // h = ix*P1 ^ iy*P2 ^ iz*P3  (uint32 wrap == numpy uint32)
    const uint32_t hx0 = ix;                         // P1 = 1
    const uint32_t hx1 = ix + 1u;
    const uint32_t hy0 = iy * 2654435761u;
    const uint32_t hy1 = hy0 + 2654435761u;          // (iy+1)*P2 mod 2^32
    const uint32_t hz0 = iz * 805459861u;
    const uint32_t hz1 = hz0 + 805459861u;

    const vfloat2* __restrict__ tl = table + (uint32_t)l * TSIZE;

    // 8 independent gathers within ONE 4 MiB slice (L2-resident this phase).
    const vfloat2 c000 = tl[(hx0 ^ hy0 ^ hz0) & TMASK];
    const vfloat2 c001 = tl[(hx0 ^ hy0 ^ hz1) & TMASK];
    const vfloat2 c010 = tl[(hx0 ^ hy1 ^ hz0) & TMASK];
    const vfloat2 c011 = tl[(hx0 ^ hy1 ^ hz1) & TMASK];
    const vfloat2 c100 = tl[(hx1 ^ hy0 ^ hz0) & TMASK];
    const vfloat2 c101 = tl[(hx1 ^ hy0 ^ hz1) & TMASK];
    const vfloat2 c110 = tl[(hx1 ^ hy1 ^ hz0) & TMASK];
    const vfloat2 c111 = tl[(hx1 ^ hy1 ^ hz1) & TMASK];

    const float wx0 = 1.0f - wx, wy0 = 1.0f - wy, wz0 = 1.0f - wz;

    float f0 = 0.0f, f1 = 0.0f;
    float w;
    // Same corner order as reference loop (dz innermost).
    w = (wx0 * wy0) * wz0; f0 += c000.x * w; f1 += c000.y * w;
    w = (wx0 * wy0) * wz;  f0 += c001.x * w; f1 += c001.y * w;
    w = (wx0 * wy ) * wz0; f0 += c010.x * w; f1 += c010.y * w;
    w = (wx0 * wy ) * wz;  f0 += c011.x * w; f1 += c011.y * w;
    w = (wx  * wy0) * wz0; f0 += c100.x * w; f1 += c100.y * w;
    w = (wx  * wy0) * wz;  f0 += c101.x * w; f1 += c101.y * w;
    w = (wx  * wy ) * wz0; f0 += c110.x * w; f1 += c110.y * w;
    w = (wx  * wy ) * wz;  f0 += c111.x * w; f1 += c111.y * w;

    vfloat2 v; v.x = f0; v.y = f1;
    __builtin_nontemporal_store(v, out + (uint32_t)n * NLEVELS + (uint32_t)l);
}

extern "C" void kernel_launch(void* const* d_in, const int* in_sizes, int n_in,
                              void* d_out, int out_size, void* d_ws, size_t ws_size,
                              hipStream_t stream) {
    const float*   x     = (const float*)d_in[0];
    const vfloat2* table = (const vfloat2*)d_in[1];
    vfloat2*       out   = (vfloat2*)d_out;

    // Exact numpy recipe in double: floor(16 * growth^l), growth = exp(ln(256)/15)
    Res16 res;
    const double growth = exp((log(4096.0) - log(16.0)) / 15.0);
    for (int l = 0; l < NLEVELS; ++l)
        res.r[l] = (float)floor(16.0 * pow(growth, (double)l));

    const dim3 block(256, 1, 1);
    const dim3 grid(NPTS / 256, NLEVELS, 1);   // 4096 x 16

    HashGridEncoder_68925635166659_kernel<<<grid, block, 0, stream>>>(x, table, out, res);
}